// Round 1
// baseline (1689.952 us; speedup 1.0000x reference)
//
#include <hip/hip_runtime.h>

#define N_NODES   50000
#define N_EDGES   800000
#define NUM_GRAPHS 256
#define IN_FEAT   64
#define REL_DIM   32
#define HID       128
#define NUM_RELS  32
#define NUM_BASES 8
#define NUM_LAYERS 2

// ---------------- Vt: Vt[l][d][b*128+j] = V[l][b][d][j] ----------------
__global__ void k_vt(const float* __restrict__ V, float* __restrict__ Vt) {
    int idx = blockIdx.x * 256 + threadIdx.x;
    if (idx >= NUM_LAYERS * NUM_BASES * HID * HID) return;
    int j = idx & 127;
    int d = (idx >> 7) & 127;
    int b = (idx >> 14) & 7;
    int l = idx >> 17;
    Vt[((size_t)l * HID + d) * 1024 + b * HID + j] = V[idx];
}

// ---------------- zero (float4 granularity) ----------------
__global__ void k_zero(float* __restrict__ p, int n4) {
    int i = blockIdx.x * 256 + threadIdx.x;
    if (i < n4) ((float4*)p)[i] = make_float4(0.f, 0.f, 0.f, 0.f);
}

// ---------------- CSR build: histogram, scan, scatter ----------------
__global__ void k_hist(const int* __restrict__ dst, int* __restrict__ deg) {
    int e = blockIdx.x * 256 + threadIdx.x;
    if (e < N_EDGES) atomicAdd(&deg[dst[e]], 1);
}

__global__ void k_scan(const int* __restrict__ deg, int* __restrict__ row_start,
                       int* __restrict__ cursor) {
    __shared__ int ssum[256];
    int tid = threadIdx.x;
    const int STRIP = (N_NODES + 255) / 256;  // 196
    int s0 = tid * STRIP;
    int local = 0;
    for (int i = 0; i < STRIP; i++) {
        int idx = s0 + i;
        if (idx < N_NODES) local += deg[idx];
    }
    ssum[tid] = local;
    __syncthreads();
    for (int off = 1; off < 256; off <<= 1) {
        int v = (tid >= off) ? ssum[tid - off] : 0;
        __syncthreads();
        ssum[tid] += v;
        __syncthreads();
    }
    int run = (tid == 0) ? 0 : ssum[tid - 1];
    for (int i = 0; i < STRIP; i++) {
        int idx = s0 + i;
        if (idx < N_NODES) {
            row_start[idx] = run;
            cursor[idx] = run;
            run += deg[idx];
        }
    }
    if (tid == 255) row_start[N_NODES] = run;
}

__global__ void k_scatter(const int* __restrict__ src, const int* __restrict__ dst,
                          const int* __restrict__ ety, int* __restrict__ cursor,
                          int* __restrict__ src_s, int* __restrict__ ety_s) {
    int e = blockIdx.x * 256 + threadIdx.x;
    if (e >= N_EDGES) return;
    int d = dst[e];
    int pos = atomicAdd(&cursor[d], 1);
    src_s[pos] = src[e];
    ety_s[pos] = ety[e];
}

// ---------------- input projection: h = relu([feat, er] @ W_in + b_in) ----------------
// 4 nodes per block of 128 threads; x staged transposed in LDS so one W row load
// feeds 4 FMAs.
__global__ void __launch_bounds__(128) k_input(
    const float* __restrict__ feat, const int* __restrict__ qrel,
    const float* __restrict__ rel_emb, const float* __restrict__ Wi,
    const float* __restrict__ bi, float* __restrict__ h, float* __restrict__ er) {
    int n0 = blockIdx.x * 4;
    int j = threadIdx.x;
    int u = j >> 5, tt = j & 31;
    __shared__ float xT[96][4];
    xT[tt][u]      = feat[(size_t)(n0 + u) * IN_FEAT + tt];
    xT[tt + 32][u] = feat[(size_t)(n0 + u) * IN_FEAT + tt + 32];
    int qr = qrel[n0 + u];
    float e = rel_emb[qr * REL_DIM + tt];
    xT[64 + tt][u] = e;
    er[(size_t)(n0 + u) * REL_DIM + tt] = e;
    __syncthreads();
    float bj = bi[j];
    float a0 = bj, a1 = bj, a2 = bj, a3 = bj;
    for (int d = 0; d < 96; d++) {
        float4 xv = *(const float4*)&xT[d][0];
        float w = Wi[d * HID + j];
        a0 = fmaf(xv.x, w, a0); a1 = fmaf(xv.y, w, a1);
        a2 = fmaf(xv.z, w, a2); a3 = fmaf(xv.w, w, a3);
    }
    h[(size_t)(n0 + 0) * HID + j] = fmaxf(a0, 0.f);
    h[(size_t)(n0 + 1) * HID + j] = fmaxf(a1, 0.f);
    h[(size_t)(n0 + 2) * HID + j] = fmaxf(a2, 0.f);
    h[(size_t)(n0 + 3) * HID + j] = fmaxf(a3, 0.f);
}

// ---------------- t = h @ Vt(group)  (M=50000, K=128, N=ncols) ----------------
// BM=BN=64, BK=64 x2, 256 threads, 4x4 register tile per thread.
__global__ void __launch_bounds__(256) k_gemm_t(
    const float* __restrict__ A, const float* __restrict__ B,
    float* __restrict__ C, int ncols) {
    __shared__ float As[64][65];
    __shared__ float Bs[64][64];
    int tid = threadIdx.x;
    int tx = tid & 15, ty = tid >> 4;
    int n0 = blockIdx.x * 64, m0 = blockIdx.y * 64;
    float acc[4][4] = {};
    int cc = (tid & 15) * 4;  // k-chunk (A) / n-chunk (B)
    int rr = tid >> 4;        // 0..15
    for (int k0 = 0; k0 < 128; k0 += 64) {
#pragma unroll
        for (int i = 0; i < 4; i++) {
            int m = rr + 16 * i;
            int row = m0 + m;
            float4 v = make_float4(0.f, 0.f, 0.f, 0.f);
            if (row < N_NODES) v = *(const float4*)&A[(size_t)row * HID + k0 + cc];
            As[cc + 0][m] = v.x; As[cc + 1][m] = v.y;
            As[cc + 2][m] = v.z; As[cc + 3][m] = v.w;
        }
#pragma unroll
        for (int i = 0; i < 4; i++) {
            int k = rr + 16 * i;
            *(float4*)&Bs[k][cc] = *(const float4*)&B[(size_t)(k0 + k) * 1024 + n0 + cc];
        }
        __syncthreads();
#pragma unroll
        for (int k = 0; k < 64; k++) {
            float4 a4 = *(const float4*)&As[k][ty * 4];
            float4 b4 = *(const float4*)&Bs[k][tx * 4];
            acc[0][0] = fmaf(a4.x, b4.x, acc[0][0]);
            acc[0][1] = fmaf(a4.x, b4.y, acc[0][1]);
            acc[0][2] = fmaf(a4.x, b4.z, acc[0][2]);
            acc[0][3] = fmaf(a4.x, b4.w, acc[0][3]);
            acc[1][0] = fmaf(a4.y, b4.x, acc[1][0]);
            acc[1][1] = fmaf(a4.y, b4.y, acc[1][1]);
            acc[1][2] = fmaf(a4.y, b4.z, acc[1][2]);
            acc[1][3] = fmaf(a4.y, b4.w, acc[1][3]);
            acc[2][0] = fmaf(a4.z, b4.x, acc[2][0]);
            acc[2][1] = fmaf(a4.z, b4.y, acc[2][1]);
            acc[2][2] = fmaf(a4.z, b4.z, acc[2][2]);
            acc[2][3] = fmaf(a4.z, b4.w, acc[2][3]);
            acc[3][0] = fmaf(a4.w, b4.x, acc[3][0]);
            acc[3][1] = fmaf(a4.w, b4.y, acc[3][1]);
            acc[3][2] = fmaf(a4.w, b4.z, acc[3][2]);
            acc[3][3] = fmaf(a4.w, b4.w, acc[3][3]);
        }
        __syncthreads();
    }
#pragma unroll
    for (int i = 0; i < 4; i++) {
        int row = m0 + ty * 4 + i;
        if (row < N_NODES)
            *(float4*)&C[(size_t)row * ncols + n0 + tx * 4] =
                make_float4(acc[i][0], acc[i][1], acc[i][2], acc[i][3]);
    }
}

// ---------------- edge mix via dst-CSR: one wave per destination node ----------------
// agg[n] (= first ? 0 : agg[n]) + sum_{e into n} sum_b c[ety,b] * t[src_e][b*128 + j]
template <int NB>
__global__ void __launch_bounds__(256) k_mix(
    const float* __restrict__ t, const float* __restrict__ comp_l,
    int b0, int first, const int* __restrict__ row_start,
    const int* __restrict__ src_s, const int* __restrict__ ety_s,
    float* __restrict__ agg) {
    int wave = threadIdx.x >> 6, lane = threadIdx.x & 63;
    int n = blockIdx.x * 4 + wave;
    int e0 = row_start[n], e1 = row_start[n + 1];
    float ax = 0.f, ay = 0.f;
    for (int e = e0; e < e1; e++) {
        int s = src_s[e], tyx = ety_s[e];
        const float* c = comp_l + tyx * NUM_BASES + b0;
        const float2* trow = (const float2*)(t + (size_t)s * (NB * HID));
#pragma unroll
        for (int b = 0; b < NB; b++) {
            float cb = c[b];
            float2 v = trow[b * 64 + lane];
            ax = fmaf(cb, v.x, ax);
            ay = fmaf(cb, v.y, ay);
        }
    }
    float* ar = agg + (size_t)n * HID + 2 * lane;
    if (first) { ar[0] = ax; ar[1] = ay; }
    else       { ar[0] += ax; ar[1] += ay; }
}

// ---------------- self loop: agg = relu(agg + h @ W_loop + b_loop) (in place) ----------------
__global__ void __launch_bounds__(128) k_update(
    const float* __restrict__ h, const float* __restrict__ Wl,
    const float* __restrict__ bl, float* __restrict__ agg) {
    int n0 = blockIdx.x * 4;
    int j = threadIdx.x;
    int u = j >> 5, tt = j & 31;
    __shared__ float hT[HID][4];
#pragma unroll
    for (int c = 0; c < 4; c++)
        hT[tt + 32 * c][u] = h[(size_t)(n0 + u) * HID + tt + 32 * c];
    __syncthreads();
    float bj = bl[j];
    float a0 = agg[(size_t)(n0 + 0) * HID + j] + bj;
    float a1 = agg[(size_t)(n0 + 1) * HID + j] + bj;
    float a2 = agg[(size_t)(n0 + 2) * HID + j] + bj;
    float a3 = agg[(size_t)(n0 + 3) * HID + j] + bj;
    for (int d = 0; d < HID; d++) {
        float4 hv = *(const float4*)&hT[d][0];
        float w = Wl[d * HID + j];
        a0 = fmaf(hv.x, w, a0); a1 = fmaf(hv.y, w, a1);
        a2 = fmaf(hv.z, w, a2); a3 = fmaf(hv.w, w, a3);
    }
    agg[(size_t)(n0 + 0) * HID + j] = fmaxf(a0, 0.f);
    agg[(size_t)(n0 + 1) * HID + j] = fmaxf(a1, 0.f);
    agg[(size_t)(n0 + 2) * HID + j] = fmaxf(a2, 0.f);
    agg[(size_t)(n0 + 3) * HID + j] = fmaxf(a3, 0.f);
}

// ---------------- attention scalar score per node ----------------
__global__ void __launch_bounds__(128) k_score(
    const float* __restrict__ h, const float* __restrict__ er,
    const float* __restrict__ Wa, const float* __restrict__ ba,
    const float* __restrict__ wsc, const float* __restrict__ bsc,
    float* __restrict__ a) {
    int n0 = blockIdx.x * 4;
    int j = threadIdx.x;
    int u = j >> 5, tt = j & 31;
    __shared__ float xT[160][4];
#pragma unroll
    for (int c = 0; c < 4; c++)
        xT[tt + 32 * c][u] = h[(size_t)(n0 + u) * HID + tt + 32 * c];
    xT[128 + tt][u] = er[(size_t)(n0 + u) * REL_DIM + tt];
    __syncthreads();
    float bj = ba[j];
    float a0 = bj, a1 = bj, a2 = bj, a3 = bj;
    for (int d = 0; d < 160; d++) {
        float4 xv = *(const float4*)&xT[d][0];
        float w = Wa[d * HID + j];
        a0 = fmaf(xv.x, w, a0); a1 = fmaf(xv.y, w, a1);
        a2 = fmaf(xv.z, w, a2); a3 = fmaf(xv.w, w, a3);
    }
    float wj = wsc[j];
    __shared__ float red[4][128];
    red[0][j] = tanhf(a0) * wj;
    red[1][j] = tanhf(a1) * wj;
    red[2][j] = tanhf(a2) * wj;
    red[3][j] = tanhf(a3) * wj;
    __syncthreads();
    for (int s = 64; s > 0; s >>= 1) {
        if (j < s) {
            red[0][j] += red[0][j + s];
            red[1][j] += red[1][j + s];
            red[2][j] += red[2][j + s];
            red[3][j] += red[3][j + s];
        }
        __syncthreads();
    }
    if (j < 4) a[n0 + j] = red[j][0] + bsc[0];
}

// ---------------- graph boundaries (graph_id is sorted) ----------------
__global__ void k_starts(const int* __restrict__ gid, int* __restrict__ starts) {
    int g = threadIdx.x;  // 0..255
    int lo = 0, hi = N_NODES;
    while (lo < hi) {
        int mid = (lo + hi) >> 1;
        if (gid[mid] < g) lo = mid + 1; else hi = mid;
    }
    starts[g] = lo;
    if (g == 0) starts[NUM_GRAPHS] = N_NODES;
}

// ---------------- segment softmax pooling + final dot ----------------
__global__ void __launch_bounds__(128) k_pool(
    const float* __restrict__ h, const float* __restrict__ a,
    const int* __restrict__ starts, const float* __restrict__ wout,
    const float* __restrict__ bout, float* __restrict__ out) {
    int g = blockIdx.x, j = threadIdx.x;
    int s0 = starts[g], s1 = starts[g + 1];
    __shared__ float red[128];
    __shared__ float exb[128];
    if (s1 <= s0) { if (j == 0) out[g] = bout[0]; return; }
    float m = -3.4e38f;
    for (int i = s0 + j; i < s1; i += 128) m = fmaxf(m, a[i]);
    red[j] = m; __syncthreads();
    for (int s = 64; s > 0; s >>= 1) {
        if (j < s) red[j] = fmaxf(red[j], red[j + s]);
        __syncthreads();
    }
    m = red[0]; __syncthreads();
    float zj = 0.f, ss = 0.f;
    for (int base = s0; base < s1; base += 128) {
        int cnt = min(128, s1 - base);
        float ev = 0.f;
        if (j < cnt) ev = expf(a[base + j] - m);
        exb[j] = ev;
        ss += ev;
        __syncthreads();
        for (int k = 0; k < cnt; k++)
            zj = fmaf(exb[k], h[(size_t)(base + k) * HID + j], zj);
        __syncthreads();
    }
    red[j] = ss; __syncthreads();
    for (int s = 64; s > 0; s >>= 1) {
        if (j < s) red[j] += red[j + s];
        __syncthreads();
    }
    ss = red[0]; __syncthreads();
    red[j] = (zj / ss) * wout[j]; __syncthreads();
    for (int s = 64; s > 0; s >>= 1) {
        if (j < s) red[j] += red[j + s];
        __syncthreads();
    }
    if (j == 0) out[g] = red[0] + bout[0];
}

extern "C" void kernel_launch(void* const* d_in, const int* in_sizes, int n_in,
                              void* d_out, int out_size, void* d_ws, size_t ws_size,
                              hipStream_t stream) {
    const float* feat    = (const float*)d_in[0];
    const int*   qrel    = (const int*)d_in[1];
    const int*   src     = (const int*)d_in[2];
    const int*   dst     = (const int*)d_in[3];
    const int*   ety     = (const int*)d_in[4];
    const int*   gid     = (const int*)d_in[5];
    const float* rel_emb = (const float*)d_in[6];
    const float* W_in    = (const float*)d_in[7];
    const float* b_in    = (const float*)d_in[8];
    const float* V       = (const float*)d_in[9];
    const float* comp    = (const float*)d_in[10];
    const float* W_loop  = (const float*)d_in[11];
    const float* b_loop  = (const float*)d_in[12];
    const float* W_attn  = (const float*)d_in[13];
    const float* b_attn  = (const float*)d_in[14];
    const float* w_sc    = (const float*)d_in[15];
    const float* b_sc    = (const float*)d_in[16];
    const float* w_out   = (const float*)d_in[17];
    const float* b_out   = (const float*)d_in[18];
    float* out = (float*)d_out;

    float* ws = (float*)d_ws;
    float* Vt = ws;                                   // 262144
    float* h0 = Vt + 262144;                          // 6.4M
    float* h1 = h0 + (size_t)N_NODES * HID;           // 6.4M
    float* er = h1 + (size_t)N_NODES * HID;           // 1.6M
    float* af = er + (size_t)N_NODES * REL_DIM;       // 50000
    int* ibase     = (int*)(af + N_NODES);
    int* starts    = ibase;                           // 260
    int* deg       = starts + 260;                    // 50000
    int* row_start = deg + 50000;                     // 50004
    int* cursor    = row_start + 50004;               // 50000
    int* src_s     = cursor + 50000;                  // 800000
    int* ety_s     = src_s + 800000;                  // 800000
    float* t = (float*)(ety_s + 800000);

    size_t used_floats = (size_t)(t - ws);
    size_t total_floats = ws_size / sizeof(float);
    size_t avail = (total_floats > used_floats) ? (total_floats - used_floats) : 0;
    int ngroups = 8;
    if (avail >= (size_t)N_NODES * 1024)      ngroups = 1;
    else if (avail >= (size_t)N_NODES * 512)  ngroups = 2;
    else if (avail >= (size_t)N_NODES * 256)  ngroups = 4;
    int nb = NUM_BASES / ngroups;
    int ncols = nb * HID;

    // --- one-time preprocessing (per call; everything recomputed deterministically) ---
    k_vt<<<1024, 256, 0, stream>>>(V, Vt);
    k_zero<<<(12500 + 255) / 256, 256, 0, stream>>>((float*)deg, 12500);
    k_hist<<<(N_EDGES + 255) / 256, 256, 0, stream>>>(dst, deg);
    k_scan<<<1, 256, 0, stream>>>(deg, row_start, cursor);
    k_scatter<<<(N_EDGES + 255) / 256, 256, 0, stream>>>(src, dst, ety, cursor, src_s, ety_s);
    k_input<<<N_NODES / 4, 128, 0, stream>>>(feat, qrel, rel_emb, W_in, b_in, h0, er);

    float* hcur = h0;
    float* hnext = h1;
    for (int l = 0; l < NUM_LAYERS; l++) {
        const float* comp_l = comp + (size_t)l * NUM_RELS * NUM_BASES;
        for (int g = 0; g < ngroups; g++) {
            const float* B = Vt + (size_t)l * 128 * 1024 + (size_t)g * ncols;
            dim3 grid(ncols / 64, (N_NODES + 63) / 64);
            k_gemm_t<<<grid, 256, 0, stream>>>(hcur, B, t, ncols);
            int b0 = g * nb;
            int first = (g == 0) ? 1 : 0;
            switch (nb) {
                case 8: k_mix<8><<<N_NODES / 4, 256, 0, stream>>>(t, comp_l, b0, first, row_start, src_s, ety_s, hnext); break;
                case 4: k_mix<4><<<N_NODES / 4, 256, 0, stream>>>(t, comp_l, b0, first, row_start, src_s, ety_s, hnext); break;
                case 2: k_mix<2><<<N_NODES / 4, 256, 0, stream>>>(t, comp_l, b0, first, row_start, src_s, ety_s, hnext); break;
                default: k_mix<1><<<N_NODES / 4, 256, 0, stream>>>(t, comp_l, b0, first, row_start, src_s, ety_s, hnext); break;
            }
        }
        k_update<<<N_NODES / 4, 128, 0, stream>>>(hcur, W_loop + (size_t)l * HID * HID,
                                                  b_loop + (size_t)l * HID, hnext);
        float* tmp = hcur; hcur = hnext; hnext = tmp;
    }

    k_score<<<N_NODES / 4, 128, 0, stream>>>(hcur, er, W_attn, b_attn, w_sc, b_sc, af);
    k_starts<<<1, 256, 0, stream>>>(gid, starts);
    k_pool<<<NUM_GRAPHS, 128, 0, stream>>>(hcur, af, starts, w_out, b_out, out);
}

// Round 2
// 1240.940 us; speedup vs baseline: 1.3618x; 1.3618x over previous
//
#include <hip/hip_runtime.h>

#define N_NODES   50000
#define N_EDGES   800000
#define NUM_GRAPHS 256
#define IN_FEAT   64
#define REL_DIM   32
#define HID       128
#define NUM_RELS  32
#define NUM_BASES 8
#define NUM_LAYERS 2

// ---------------- zero (float4 granularity) ----------------
__global__ void k_zero(float* __restrict__ p, int n4) {
    int i = blockIdx.x * 256 + threadIdx.x;
    if (i < n4) ((float4*)p)[i] = make_float4(0.f, 0.f, 0.f, 0.f);
}

// ---------------- CSR build: histogram, scan, scatter ----------------
__global__ void k_hist(const int* __restrict__ dst, int* __restrict__ deg) {
    int e = blockIdx.x * 256 + threadIdx.x;
    if (e < N_EDGES) atomicAdd(&deg[dst[e]], 1);
}

__global__ void k_scan(const int* __restrict__ deg, int* __restrict__ row_start,
                       int* __restrict__ cursor) {
    __shared__ int ssum[256];
    int tid = threadIdx.x;
    const int STRIP = (N_NODES + 255) / 256;  // 196
    int s0 = tid * STRIP;
    int local = 0;
    for (int i = 0; i < STRIP; i++) {
        int idx = s0 + i;
        if (idx < N_NODES) local += deg[idx];
    }
    ssum[tid] = local;
    __syncthreads();
    for (int off = 1; off < 256; off <<= 1) {
        int v = (tid >= off) ? ssum[tid - off] : 0;
        __syncthreads();
        ssum[tid] += v;
        __syncthreads();
    }
    int run = (tid == 0) ? 0 : ssum[tid - 1];
    for (int i = 0; i < STRIP; i++) {
        int idx = s0 + i;
        if (idx < N_NODES) {
            row_start[idx] = run;
            cursor[idx] = run;
            run += deg[idx];
        }
    }
    if (tid == 255) row_start[N_NODES] = run;
}

__global__ void k_scatter(const int* __restrict__ src, const int* __restrict__ dst,
                          const int* __restrict__ ety, int* __restrict__ cursor,
                          int2* __restrict__ edge_s) {
    int e = blockIdx.x * 256 + threadIdx.x;
    if (e >= N_EDGES) return;
    int d = dst[e];
    int pos = atomicAdd(&cursor[d], 1);
    edge_s[pos] = make_int2(src[e], ety[e]);
}

// ---------------- input projection: h = relu([feat, er] @ W_in + b_in) ----------------
__global__ void __launch_bounds__(128) k_input(
    const float* __restrict__ feat, const int* __restrict__ qrel,
    const float* __restrict__ rel_emb, const float* __restrict__ Wi,
    const float* __restrict__ bi, float* __restrict__ h, float* __restrict__ er) {
    int n0 = blockIdx.x * 4;
    int j = threadIdx.x;
    int u = j >> 5, tt = j & 31;
    __shared__ float xT[96][4];
    xT[tt][u]      = feat[(size_t)(n0 + u) * IN_FEAT + tt];
    xT[tt + 32][u] = feat[(size_t)(n0 + u) * IN_FEAT + tt + 32];
    int qr = qrel[n0 + u];
    float e = rel_emb[qr * REL_DIM + tt];
    xT[64 + tt][u] = e;
    er[(size_t)(n0 + u) * REL_DIM + tt] = e;
    __syncthreads();
    float bj = bi[j];
    float a0 = bj, a1 = bj, a2 = bj, a3 = bj;
    for (int d = 0; d < 96; d++) {
        float4 xv = *(const float4*)&xT[d][0];
        float w = Wi[d * HID + j];
        a0 = fmaf(xv.x, w, a0); a1 = fmaf(xv.y, w, a1);
        a2 = fmaf(xv.z, w, a2); a3 = fmaf(xv.w, w, a3);
    }
    h[(size_t)(n0 + 0) * HID + j] = fmaxf(a0, 0.f);
    h[(size_t)(n0 + 1) * HID + j] = fmaxf(a1, 0.f);
    h[(size_t)(n0 + 2) * HID + j] = fmaxf(a2, 0.f);
    h[(size_t)(n0 + 3) * HID + j] = fmaxf(a3, 0.f);
}

// ---------------- per-dst basis-weighted gather: G[n-c0, b*128+d] = sum_e c[ety,b]*h[src,d] ----------------
__global__ void __launch_bounds__(256) k_mix2(
    const float* __restrict__ h, const float* __restrict__ comp_l,
    const int* __restrict__ row_start, const int2* __restrict__ edge_s,
    float* __restrict__ G, int c0, int nc) {
    __shared__ float cs[NUM_RELS * NUM_BASES];
    if (threadIdx.x < NUM_RELS * NUM_BASES) cs[threadIdx.x] = comp_l[threadIdx.x];
    __syncthreads();
    int wave = threadIdx.x >> 6, lane = threadIdx.x & 63;
    int n = c0 + blockIdx.x * 4 + wave;
    if (n >= c0 + nc) return;
    int e0 = row_start[n], e1 = row_start[n + 1];
    float2 acc[NUM_BASES];
#pragma unroll
    for (int b = 0; b < NUM_BASES; b++) acc[b] = make_float2(0.f, 0.f);
    for (int e = e0; e < e1; e++) {
        int2 se = edge_s[e];
        const float* c = &cs[se.y * NUM_BASES];
        float2 v = ((const float2*)(h + (size_t)se.x * HID))[lane];
#pragma unroll
        for (int b = 0; b < NUM_BASES; b++) {
            acc[b].x = fmaf(c[b], v.x, acc[b].x);
            acc[b].y = fmaf(c[b], v.y, acc[b].y);
        }
    }
    float2* gr = (float2*)(G + (size_t)(n - c0) * 1024);
#pragma unroll
    for (int b = 0; b < NUM_BASES; b++) gr[b * 64 + lane] = acc[b];
}

// ---------------- fused: out = relu([G | h] @ [Vl ; Wl] + bl) ----------------
// M = nc (chunk rows), K = 1152, N = 128. BM=64, BN=128, BK=32, 256 threads, 8x4/thread.
__global__ void __launch_bounds__(256) k_gemm2(
    const float* __restrict__ G, const float* __restrict__ h,
    const float* __restrict__ Vl, const float* __restrict__ Wl,
    const float* __restrict__ bl, float* __restrict__ out,
    int c0, int nc) {
    __shared__ float As[32][64];
    __shared__ float Bs[32][128];
    int tid = threadIdx.x;
    int tx = tid & 31, ty = tid >> 5;
    int m0 = blockIdx.y * 64;
    float acc[8][4] = {};
    for (int k0 = 0; k0 < 1152; k0 += 32) {
        // stage A (transposed into As[k][m])
#pragma unroll
        for (int it = 0; it < 2; it++) {
            int p = tid + it * 256;      // 0..511
            int m = p & 63;
            int k4 = (p >> 6) << 2;      // 0,4,...,28
            int row = m0 + m;
            float4 v = make_float4(0.f, 0.f, 0.f, 0.f);
            if (row < nc) {
                if (k0 < 1024)
                    v = *(const float4*)&G[(size_t)row * 1024 + k0 + k4];
                else
                    v = *(const float4*)&h[(size_t)(c0 + row) * HID + (k0 - 1024) + k4];
            }
            As[k4 + 0][m] = v.x; As[k4 + 1][m] = v.y;
            As[k4 + 2][m] = v.z; As[k4 + 3][m] = v.w;
        }
        // stage B
#pragma unroll
        for (int it = 0; it < 4; it++) {
            int p = tid + it * 256;      // 0..1023
            int j = (p & 31) << 2;
            int k = p >> 5;
            const float* Bsrc = (k0 < 1024) ? &Vl[(size_t)(k0 + k) * 128 + j]
                                            : &Wl[(size_t)(k0 - 1024 + k) * 128 + j];
            *(float4*)&Bs[k][j] = *(const float4*)Bsrc;
        }
        __syncthreads();
#pragma unroll
        for (int k = 0; k < 32; k++) {
            float4 a0 = *(const float4*)&As[k][ty * 8];
            float4 a1 = *(const float4*)&As[k][ty * 8 + 4];
            float4 b4 = *(const float4*)&Bs[k][tx * 4];
            float av[8] = {a0.x, a0.y, a0.z, a0.w, a1.x, a1.y, a1.z, a1.w};
#pragma unroll
            for (int i = 0; i < 8; i++) {
                acc[i][0] = fmaf(av[i], b4.x, acc[i][0]);
                acc[i][1] = fmaf(av[i], b4.y, acc[i][1]);
                acc[i][2] = fmaf(av[i], b4.z, acc[i][2]);
                acc[i][3] = fmaf(av[i], b4.w, acc[i][3]);
            }
        }
        __syncthreads();
    }
    float4 bias = *(const float4*)&bl[tx * 4];
#pragma unroll
    for (int i = 0; i < 8; i++) {
        int row = m0 + ty * 8 + i;
        if (row < nc) {
            float4 r;
            r.x = fmaxf(acc[i][0] + bias.x, 0.f);
            r.y = fmaxf(acc[i][1] + bias.y, 0.f);
            r.z = fmaxf(acc[i][2] + bias.z, 0.f);
            r.w = fmaxf(acc[i][3] + bias.w, 0.f);
            *(float4*)&out[(size_t)(c0 + row) * HID + tx * 4] = r;
        }
    }
}

// ---------------- attention scalar score per node ----------------
__global__ void __launch_bounds__(128) k_score(
    const float* __restrict__ h, const float* __restrict__ er,
    const float* __restrict__ Wa, const float* __restrict__ ba,
    const float* __restrict__ wsc, const float* __restrict__ bsc,
    float* __restrict__ a) {
    int n0 = blockIdx.x * 4;
    int j = threadIdx.x;
    int u = j >> 5, tt = j & 31;
    __shared__ float xT[160][4];
#pragma unroll
    for (int c = 0; c < 4; c++)
        xT[tt + 32 * c][u] = h[(size_t)(n0 + u) * HID + tt + 32 * c];
    xT[128 + tt][u] = er[(size_t)(n0 + u) * REL_DIM + tt];
    __syncthreads();
    float bj = ba[j];
    float a0 = bj, a1 = bj, a2 = bj, a3 = bj;
    for (int d = 0; d < 160; d++) {
        float4 xv = *(const float4*)&xT[d][0];
        float w = Wa[d * HID + j];
        a0 = fmaf(xv.x, w, a0); a1 = fmaf(xv.y, w, a1);
        a2 = fmaf(xv.z, w, a2); a3 = fmaf(xv.w, w, a3);
    }
    float wj = wsc[j];
    __shared__ float red[4][128];
    red[0][j] = tanhf(a0) * wj;
    red[1][j] = tanhf(a1) * wj;
    red[2][j] = tanhf(a2) * wj;
    red[3][j] = tanhf(a3) * wj;
    __syncthreads();
    for (int s = 64; s > 0; s >>= 1) {
        if (j < s) {
            red[0][j] += red[0][j + s];
            red[1][j] += red[1][j + s];
            red[2][j] += red[2][j + s];
            red[3][j] += red[3][j + s];
        }
        __syncthreads();
    }
    if (j < 4) a[n0 + j] = red[j][0] + bsc[0];
}

// ---------------- graph boundaries (graph_id is sorted) ----------------
__global__ void k_starts(const int* __restrict__ gid, int* __restrict__ starts) {
    int g = threadIdx.x;  // 0..255
    int lo = 0, hi = N_NODES;
    while (lo < hi) {
        int mid = (lo + hi) >> 1;
        if (gid[mid] < g) lo = mid + 1; else hi = mid;
    }
    starts[g] = lo;
    if (g == 0) starts[NUM_GRAPHS] = N_NODES;
}

// ---------------- segment softmax pooling + final dot ----------------
__global__ void __launch_bounds__(128) k_pool(
    const float* __restrict__ h, const float* __restrict__ a,
    const int* __restrict__ starts, const float* __restrict__ wout,
    const float* __restrict__ bout, float* __restrict__ out) {
    int g = blockIdx.x, j = threadIdx.x;
    int s0 = starts[g], s1 = starts[g + 1];
    __shared__ float red[128];
    __shared__ float exb[128];
    if (s1 <= s0) { if (j == 0) out[g] = bout[0]; return; }
    float m = -3.4e38f;
    for (int i = s0 + j; i < s1; i += 128) m = fmaxf(m, a[i]);
    red[j] = m; __syncthreads();
    for (int s = 64; s > 0; s >>= 1) {
        if (j < s) red[j] = fmaxf(red[j], red[j + s]);
        __syncthreads();
    }
    m = red[0]; __syncthreads();
    float zj = 0.f, ss = 0.f;
    for (int base = s0; base < s1; base += 128) {
        int cnt = min(128, s1 - base);
        float ev = 0.f;
        if (j < cnt) ev = expf(a[base + j] - m);
        exb[j] = ev;
        ss += ev;
        __syncthreads();
        for (int k = 0; k < cnt; k++)
            zj = fmaf(exb[k], h[(size_t)(base + k) * HID + j], zj);
        __syncthreads();
    }
    red[j] = ss; __syncthreads();
    for (int s = 64; s > 0; s >>= 1) {
        if (j < s) red[j] += red[j + s];
        __syncthreads();
    }
    ss = red[0]; __syncthreads();
    red[j] = (zj / ss) * wout[j]; __syncthreads();
    for (int s = 64; s > 0; s >>= 1) {
        if (j < s) red[j] += red[j + s];
        __syncthreads();
    }
    if (j == 0) out[g] = red[0] + bout[0];
}

extern "C" void kernel_launch(void* const* d_in, const int* in_sizes, int n_in,
                              void* d_out, int out_size, void* d_ws, size_t ws_size,
                              hipStream_t stream) {
    const float* feat    = (const float*)d_in[0];
    const int*   qrel    = (const int*)d_in[1];
    const int*   src     = (const int*)d_in[2];
    const int*   dst     = (const int*)d_in[3];
    const int*   ety     = (const int*)d_in[4];
    const int*   gid     = (const int*)d_in[5];
    const float* rel_emb = (const float*)d_in[6];
    const float* W_in    = (const float*)d_in[7];
    const float* b_in    = (const float*)d_in[8];
    const float* V       = (const float*)d_in[9];
    const float* comp    = (const float*)d_in[10];
    const float* W_loop  = (const float*)d_in[11];
    const float* b_loop  = (const float*)d_in[12];
    const float* W_attn  = (const float*)d_in[13];
    const float* b_attn  = (const float*)d_in[14];
    const float* w_sc    = (const float*)d_in[15];
    const float* b_sc    = (const float*)d_in[16];
    const float* w_out   = (const float*)d_in[17];
    const float* b_out   = (const float*)d_in[18];
    float* out = (float*)d_out;

    float* ws = (float*)d_ws;
    float* h0 = ws;                                   // 6.4M floats
    float* h1 = h0 + (size_t)N_NODES * HID;           // 6.4M
    float* er = h1 + (size_t)N_NODES * HID;           // 1.6M
    float* af = er + (size_t)N_NODES * REL_DIM;       // 50000
    int* starts    = (int*)(af + N_NODES);            // 260
    int* deg       = starts + 260;                    // 50000
    int* row_start = deg + 50000;                     // 50004
    int* cursor    = row_start + 50004;               // 50000
    int2* edge_s   = (int2*)(cursor + 50000);         // 800000 int2
    float* G = (float*)(edge_s + 800000);

    size_t used_floats = (size_t)(G - ws);
    size_t total_floats = ws_size / sizeof(float);
    size_t avail = (total_floats > used_floats) ? (total_floats - used_floats) : 0;
    long long NC = (long long)(avail / 1024);         // G rows that fit
    NC = (NC / 64) * 64;
    if (NC > 50048) NC = 50048;
    if (NC < 64) NC = 64;

    // --- preprocessing ---
    k_zero<<<(12500 + 255) / 256, 256, 0, stream>>>((float*)deg, 12500);
    k_hist<<<(N_EDGES + 255) / 256, 256, 0, stream>>>(dst, deg);
    k_scan<<<1, 256, 0, stream>>>(deg, row_start, cursor);
    k_scatter<<<(N_EDGES + 255) / 256, 256, 0, stream>>>(src, dst, ety, cursor, edge_s);
    k_input<<<N_NODES / 4, 128, 0, stream>>>(feat, qrel, rel_emb, W_in, b_in, h0, er);

    float* hcur = h0;
    float* hnext = h1;
    for (int l = 0; l < NUM_LAYERS; l++) {
        const float* comp_l = comp + (size_t)l * NUM_RELS * NUM_BASES;
        const float* Vl = V + (size_t)l * NUM_BASES * HID * HID;   // [1024][128]
        const float* Wl = W_loop + (size_t)l * HID * HID;
        const float* bl = b_loop + (size_t)l * HID;
        for (int c0 = 0; c0 < N_NODES; c0 += (int)NC) {
            int nc = (int)((N_NODES - c0 < NC) ? (N_NODES - c0) : NC);
            k_mix2<<<(nc + 3) / 4, 256, 0, stream>>>(hcur, comp_l, row_start, edge_s, G, c0, nc);
            dim3 grid(1, (nc + 63) / 64);
            k_gemm2<<<grid, 256, 0, stream>>>(G, hcur, Vl, Wl, bl, hnext, c0, nc);
        }
        float* tmp = hcur; hcur = hnext; hnext = tmp;
    }

    k_score<<<N_NODES / 4, 128, 0, stream>>>(hcur, er, W_attn, b_attn, w_sc, b_sc, af);
    k_starts<<<1, 256, 0, stream>>>(gid, starts);
    k_pool<<<NUM_GRAPHS, 128, 0, stream>>>(hcur, af, starts, w_out, b_out, out);
}

// Round 3
// 908.376 us; speedup vs baseline: 1.8604x; 1.3661x over previous
//
#include <hip/hip_runtime.h>

#define N_NODES   50000
#define N_EDGES   800000
#define NUM_GRAPHS 256
#define IN_FEAT   64
#define REL_DIM   32
#define HID       128
#define NUM_RELS  32
#define NUM_BASES 8
#define NUM_LAYERS 2

typedef __attribute__((ext_vector_type(8))) short bf16x8;
typedef __attribute__((ext_vector_type(4))) float f32x4;

// ---------------- zero (float4 granularity) ----------------
__global__ void k_zero(float* __restrict__ p, int n4) {
    int i = blockIdx.x * 256 + threadIdx.x;
    if (i < n4) ((float4*)p)[i] = make_float4(0.f, 0.f, 0.f, 0.f);
}

// ---------------- CSR build: histogram, scan, scatter ----------------
__global__ void k_hist(const int* __restrict__ dst, int* __restrict__ deg) {
    int e = blockIdx.x * 256 + threadIdx.x;
    if (e < N_EDGES) atomicAdd(&deg[dst[e]], 1);
}

__global__ void k_scan(const int* __restrict__ deg, int* __restrict__ row_start,
                       int* __restrict__ cursor) {
    __shared__ int ssum[256];
    int tid = threadIdx.x;
    const int STRIP = (N_NODES + 255) / 256;  // 196
    int s0 = tid * STRIP;
    int local = 0;
    for (int i = 0; i < STRIP; i++) {
        int idx = s0 + i;
        if (idx < N_NODES) local += deg[idx];
    }
    ssum[tid] = local;
    __syncthreads();
    for (int off = 1; off < 256; off <<= 1) {
        int v = (tid >= off) ? ssum[tid - off] : 0;
        __syncthreads();
        ssum[tid] += v;
        __syncthreads();
    }
    int run = (tid == 0) ? 0 : ssum[tid - 1];
    for (int i = 0; i < STRIP; i++) {
        int idx = s0 + i;
        if (idx < N_NODES) {
            row_start[idx] = run;
            cursor[idx] = run;
            run += deg[idx];
        }
    }
    if (tid == 255) row_start[N_NODES] = run;
}

__global__ void k_scatter(const int* __restrict__ src, const int* __restrict__ dst,
                          const int* __restrict__ ety, int* __restrict__ cursor,
                          int2* __restrict__ edge_s) {
    int e = blockIdx.x * 256 + threadIdx.x;
    if (e >= N_EDGES) return;
    int d = dst[e];
    int pos = atomicAdd(&cursor[d], 1);
    edge_s[pos] = make_int2(src[e], ety[e]);
}

// ---------------- input projection: h = relu([feat, er] @ W_in + b_in) ----------------
__global__ void __launch_bounds__(128) k_input(
    const float* __restrict__ feat, const int* __restrict__ qrel,
    const float* __restrict__ rel_emb, const float* __restrict__ Wi,
    const float* __restrict__ bi, float* __restrict__ h, float* __restrict__ er) {
    int n0 = blockIdx.x * 4;
    int j = threadIdx.x;
    int u = j >> 5, tt = j & 31;
    __shared__ float xT[96][4];
    xT[tt][u]      = feat[(size_t)(n0 + u) * IN_FEAT + tt];
    xT[tt + 32][u] = feat[(size_t)(n0 + u) * IN_FEAT + tt + 32];
    int qr = qrel[n0 + u];
    float e = rel_emb[qr * REL_DIM + tt];
    xT[64 + tt][u] = e;
    er[(size_t)(n0 + u) * REL_DIM + tt] = e;
    __syncthreads();
    float bj = bi[j];
    float a0 = bj, a1 = bj, a2 = bj, a3 = bj;
    for (int d = 0; d < 96; d++) {
        float4 xv = *(const float4*)&xT[d][0];
        float w = Wi[d * HID + j];
        a0 = fmaf(xv.x, w, a0); a1 = fmaf(xv.y, w, a1);
        a2 = fmaf(xv.z, w, a2); a3 = fmaf(xv.w, w, a3);
    }
    h[(size_t)(n0 + 0) * HID + j] = fmaxf(a0, 0.f);
    h[(size_t)(n0 + 1) * HID + j] = fmaxf(a1, 0.f);
    h[(size_t)(n0 + 2) * HID + j] = fmaxf(a2, 0.f);
    h[(size_t)(n0 + 3) * HID + j] = fmaxf(a3, 0.f);
}

// ---------------- per-dst basis-weighted gather: G[n-c0, b*128+d] = sum_e c[ety,b]*h[src,d] ----------------
__global__ void __launch_bounds__(256) k_mix2(
    const float* __restrict__ h, const float* __restrict__ comp_l,
    const int* __restrict__ row_start, const int2* __restrict__ edge_s,
    float* __restrict__ G, int c0, int nc) {
    __shared__ float cs[NUM_RELS * NUM_BASES];
    if (threadIdx.x < NUM_RELS * NUM_BASES) cs[threadIdx.x] = comp_l[threadIdx.x];
    __syncthreads();
    int wave = threadIdx.x >> 6, lane = threadIdx.x & 63;
    int n = c0 + blockIdx.x * 4 + wave;
    if (n >= c0 + nc) return;
    int e0 = row_start[n], e1 = row_start[n + 1];
    float2 acc[NUM_BASES];
#pragma unroll
    for (int b = 0; b < NUM_BASES; b++) acc[b] = make_float2(0.f, 0.f);
    for (int e = e0; e < e1; e++) {
        int2 se = edge_s[e];
        const float* c = &cs[se.y * NUM_BASES];
        float2 v = ((const float2*)(h + (size_t)se.x * HID))[lane];
#pragma unroll
        for (int b = 0; b < NUM_BASES; b++) {
            acc[b].x = fmaf(c[b], v.x, acc[b].x);
            acc[b].y = fmaf(c[b], v.y, acc[b].y);
        }
    }
    float2* gr = (float2*)(G + (size_t)(n - c0) * 1024);
#pragma unroll
    for (int b = 0; b < NUM_BASES; b++) gr[b * 64 + lane] = acc[b];
}

// ---------------- B fragment table: hi/lo bf16 of [Vl ; Wl] in MFMA fragment order ----------------
// entry (l, s, t, lane): 16 ushort = hi[8], lo[8];
// element j: B[k = s*32 + (lane>>4)*8 + j][col = t*16 + (lane&15)] of layer l.
__global__ void k_bfrag(const float* __restrict__ V, const float* __restrict__ W_loop,
                        unsigned short* __restrict__ Bf) {
    int idx = blockIdx.x * 256 + threadIdx.x;
    if (idx >= NUM_LAYERS * 36 * 8 * 64) return;
    int lane = idx & 63;
    int t = (idx >> 6) & 7;
    int s = (idx >> 9) % 36;
    int l = (idx >> 9) / 36;
    int col = t * 16 + (lane & 15);
    int kbase = s * 32 + (lane >> 4) * 8;
    unsigned short* o = Bf + (size_t)idx * 16;
#pragma unroll
    for (int j = 0; j < 8; j++) {
        int k = kbase + j;
        float f = (k < 1024) ? V[((size_t)l * 1024 + k) * HID + col]
                             : W_loop[((size_t)l * HID + (k - 1024)) * HID + col];
        unsigned u = __builtin_bit_cast(unsigned, f);
        unsigned r = (u + 0x7fffu + ((u >> 16) & 1u)) & 0xffff0000u;
        float fh = __builtin_bit_cast(float, r);
        float fl = f - fh;
        unsigned u2 = __builtin_bit_cast(unsigned, fl);
        unsigned r2 = (u2 + 0x7fffu + ((u2 >> 16) & 1u)) >> 16;
        o[j] = (unsigned short)(r >> 16);
        o[8 + j] = (unsigned short)r2;
    }
}

__device__ inline void split8(float4 a0, float4 a1, bf16x8& hi, bf16x8& lo) {
    float f[8] = {a0.x, a0.y, a0.z, a0.w, a1.x, a1.y, a1.z, a1.w};
#pragma unroll
    for (int j = 0; j < 8; j++) {
        unsigned u = __builtin_bit_cast(unsigned, f[j]);
        unsigned r = (u + 0x7fffu + ((u >> 16) & 1u)) & 0xffff0000u;
        float fh = __builtin_bit_cast(float, r);
        float fl = f[j] - fh;
        unsigned u2 = __builtin_bit_cast(unsigned, fl);
        unsigned r2 = (u2 + 0x7fffu + ((u2 >> 16) & 1u)) >> 16;
        hi[j] = (short)(r >> 16);
        lo[j] = (short)r2;
    }
}

// ---------------- MFMA GEMM: out = relu([G | h] @ [Vl ; Wl] + bl) ----------------
// M = nc, K = 1152, N = 128. Block: 4 waves = 2 row-groups(16) x 2 K-halves(576).
// A split to bf16 hi/lo on the fly; 3 MFMA per tile (AhBh + AlBh + AhBl).
__global__ void __launch_bounds__(256) k_gemm3(
    const float* __restrict__ G, const float* __restrict__ h,
    const unsigned short* __restrict__ Bf, const float* __restrict__ bl,
    float* __restrict__ out, int c0, int nc) {
    __shared__ float lred[2][16][132];
    int tid = threadIdx.x;
    int lane = tid & 63;
    int wid = tid >> 6;
    int wr = wid & 1, wk = wid >> 1;
    int r0 = blockIdx.x * 32 + wr * 16;
    int rit = lane & 15, kg = lane >> 4;
    int arow = r0 + rit;              // A-side row this lane feeds
    f32x4 acc[8] = {};
    int s_lo = wk * 18, s_hi = s_lo + 18;
    for (int s = s_lo; s < s_hi; s++) {
        int k0 = s * 32;
        const float* ap = (k0 < 1024)
            ? (G + (size_t)arow * 1024 + k0 + kg * 8)
            : (h + (size_t)(c0 + arow) * HID + (k0 - 1024) + kg * 8);
        float4 a0 = *(const float4*)ap;
        float4 a1 = *(const float4*)(ap + 4);
        bf16x8 ah, al;
        split8(a0, a1, ah, al);
        const bf16x8* bp = (const bf16x8*)Bf + ((size_t)(s * 8) * 64 + lane) * 2;
#pragma unroll
        for (int t = 0; t < 8; t++) {
            bf16x8 bh = bp[0];
            bf16x8 blo = bp[1];
            acc[t] = __builtin_amdgcn_mfma_f32_16x16x32_bf16(ah, bh, acc[t], 0, 0, 0);
            acc[t] = __builtin_amdgcn_mfma_f32_16x16x32_bf16(al, bh, acc[t], 0, 0, 0);
            acc[t] = __builtin_amdgcn_mfma_f32_16x16x32_bf16(ah, blo, acc[t], 0, 0, 0);
            bp += 128;
        }
    }
    // combine K-halves: wk==1 dumps partials to LDS, wk==0 adds + epilogue.
    if (wk == 1) {
#pragma unroll
        for (int t = 0; t < 8; t++)
#pragma unroll
            for (int q = 0; q < 4; q++)
                lred[wr][kg * 4 + q][t * 16 + rit] = acc[t][q];
    }
    __syncthreads();
    if (wk == 0) {
#pragma unroll
        for (int t = 0; t < 8; t++) {
            int col = t * 16 + rit;
            float b = bl[col];
#pragma unroll
            for (int q = 0; q < 4; q++) {
                int row = r0 + kg * 4 + q;   // C-side row (differs from A-side lane row)
                if (row < nc) {
                    float v = acc[t][q] + lred[wr][kg * 4 + q][col] + b;
                    out[(size_t)(c0 + row) * HID + col] = fmaxf(v, 0.f);
                }
            }
        }
    }
}

// ---------------- attention scalar score per node ----------------
__global__ void __launch_bounds__(128) k_score(
    const float* __restrict__ h, const float* __restrict__ er,
    const float* __restrict__ Wa, const float* __restrict__ ba,
    const float* __restrict__ wsc, const float* __restrict__ bsc,
    float* __restrict__ a) {
    int n0 = blockIdx.x * 4;
    int j = threadIdx.x;
    int u = j >> 5, tt = j & 31;
    __shared__ float xT[160][4];
#pragma unroll
    for (int c = 0; c < 4; c++)
        xT[tt + 32 * c][u] = h[(size_t)(n0 + u) * HID + tt + 32 * c];
    xT[128 + tt][u] = er[(size_t)(n0 + u) * REL_DIM + tt];
    __syncthreads();
    float bj = ba[j];
    float a0 = bj, a1 = bj, a2 = bj, a3 = bj;
    for (int d = 0; d < 160; d++) {
        float4 xv = *(const float4*)&xT[d][0];
        float w = Wa[d * HID + j];
        a0 = fmaf(xv.x, w, a0); a1 = fmaf(xv.y, w, a1);
        a2 = fmaf(xv.z, w, a2); a3 = fmaf(xv.w, w, a3);
    }
    float wj = wsc[j];
    __shared__ float red[4][128];
    red[0][j] = tanhf(a0) * wj;
    red[1][j] = tanhf(a1) * wj;
    red[2][j] = tanhf(a2) * wj;
    red[3][j] = tanhf(a3) * wj;
    __syncthreads();
    for (int s = 64; s > 0; s >>= 1) {
        if (j < s) {
            red[0][j] += red[0][j + s];
            red[1][j] += red[1][j + s];
            red[2][j] += red[2][j + s];
            red[3][j] += red[3][j + s];
        }
        __syncthreads();
    }
    if (j < 4) a[n0 + j] = red[j][0] + bsc[0];
}

// ---------------- graph boundaries (graph_id is sorted) ----------------
__global__ void k_starts(const int* __restrict__ gid, int* __restrict__ starts) {
    int g = threadIdx.x;  // 0..255
    int lo = 0, hi = N_NODES;
    while (lo < hi) {
        int mid = (lo + hi) >> 1;
        if (gid[mid] < g) lo = mid + 1; else hi = mid;
    }
    starts[g] = lo;
    if (g == 0) starts[NUM_GRAPHS] = N_NODES;
}

// ---------------- segment softmax pooling + final dot ----------------
__global__ void __launch_bounds__(128) k_pool(
    const float* __restrict__ h, const float* __restrict__ a,
    const int* __restrict__ starts, const float* __restrict__ wout,
    const float* __restrict__ bout, float* __restrict__ out) {
    int g = blockIdx.x, j = threadIdx.x;
    int s0 = starts[g], s1 = starts[g + 1];
    __shared__ float red[128];
    __shared__ float exb[128];
    if (s1 <= s0) { if (j == 0) out[g] = bout[0]; return; }
    float m = -3.4e38f;
    for (int i = s0 + j; i < s1; i += 128) m = fmaxf(m, a[i]);
    red[j] = m; __syncthreads();
    for (int s = 64; s > 0; s >>= 1) {
        if (j < s) red[j] = fmaxf(red[j], red[j + s]);
        __syncthreads();
    }
    m = red[0]; __syncthreads();
    float zj = 0.f, ss = 0.f;
    for (int base = s0; base < s1; base += 128) {
        int cnt = min(128, s1 - base);
        float ev = 0.f;
        if (j < cnt) ev = expf(a[base + j] - m);
        exb[j] = ev;
        ss += ev;
        __syncthreads();
        for (int k = 0; k < cnt; k++)
            zj = fmaf(exb[k], h[(size_t)(base + k) * HID + j], zj);
        __syncthreads();
    }
    red[j] = ss; __syncthreads();
    for (int s = 64; s > 0; s >>= 1) {
        if (j < s) red[j] += red[j + s];
        __syncthreads();
    }
    ss = red[0]; __syncthreads();
    red[j] = (zj / ss) * wout[j]; __syncthreads();
    for (int s = 64; s > 0; s >>= 1) {
        if (j < s) red[j] += red[j + s];
        __syncthreads();
    }
    if (j == 0) out[g] = red[0] + bout[0];
}

extern "C" void kernel_launch(void* const* d_in, const int* in_sizes, int n_in,
                              void* d_out, int out_size, void* d_ws, size_t ws_size,
                              hipStream_t stream) {
    const float* feat    = (const float*)d_in[0];
    const int*   qrel    = (const int*)d_in[1];
    const int*   src     = (const int*)d_in[2];
    const int*   dst     = (const int*)d_in[3];
    const int*   ety     = (const int*)d_in[4];
    const int*   gid     = (const int*)d_in[5];
    const float* rel_emb = (const float*)d_in[6];
    const float* W_in    = (const float*)d_in[7];
    const float* b_in    = (const float*)d_in[8];
    const float* V       = (const float*)d_in[9];
    const float* comp    = (const float*)d_in[10];
    const float* W_loop  = (const float*)d_in[11];
    const float* b_loop  = (const float*)d_in[12];
    const float* W_attn  = (const float*)d_in[13];
    const float* b_attn  = (const float*)d_in[14];
    const float* w_sc    = (const float*)d_in[15];
    const float* b_sc    = (const float*)d_in[16];
    const float* w_out   = (const float*)d_in[17];
    const float* b_out   = (const float*)d_in[18];
    float* out = (float*)d_out;

    float* ws = (float*)d_ws;
    float* h0 = ws;                                   // 6.4M floats
    float* h1 = h0 + (size_t)N_NODES * HID;           // 6.4M
    float* er = h1 + (size_t)N_NODES * HID;           // 1.6M
    float* af = er + (size_t)N_NODES * REL_DIM;       // 50000
    int* starts    = (int*)(af + N_NODES);            // 260
    int* deg       = starts + 260;                    // 50000
    int* row_start = deg + 50000;                     // 50004
    int* cursor    = row_start + 50004;               // 50000
    int2* edge_s   = (int2*)(cursor + 50000);         // 800000 int2
    unsigned short* Bf = (unsigned short*)(edge_s + 800000);  // 2*36*8*64*16 ushort
    const size_t BF_USHORT = (size_t)NUM_LAYERS * 36 * 8 * 64 * 16;
    float* G = (float*)(Bf + BF_USHORT);

    size_t used_floats = (size_t)(G - ws);
    size_t total_floats = ws_size / sizeof(float);
    size_t avail = (total_floats > used_floats) ? (total_floats - used_floats) : 0;
    long long NC = (long long)(avail / 1024);         // G rows that fit
    NC = (NC / 64) * 64;
    if (NC > 50048) NC = 50048;
    if (NC < 64) NC = 64;

    // --- preprocessing ---
    k_zero<<<(12500 + 255) / 256, 256, 0, stream>>>((float*)deg, 12500);
    k_hist<<<(N_EDGES + 255) / 256, 256, 0, stream>>>(dst, deg);
    k_scan<<<1, 256, 0, stream>>>(deg, row_start, cursor);
    k_scatter<<<(N_EDGES + 255) / 256, 256, 0, stream>>>(src, dst, ety, cursor, edge_s);
    k_bfrag<<<(NUM_LAYERS * 36 * 8 * 64 + 255) / 256, 256, 0, stream>>>(V, W_loop, Bf);
    k_input<<<N_NODES / 4, 128, 0, stream>>>(feat, qrel, rel_emb, W_in, b_in, h0, er);

    float* hcur = h0;
    float* hnext = h1;
    for (int l = 0; l < NUM_LAYERS; l++) {
        const float* comp_l = comp + (size_t)l * NUM_RELS * NUM_BASES;
        const unsigned short* Bfl = Bf + (size_t)l * 36 * 8 * 64 * 16;
        const float* bl = b_loop + (size_t)l * HID;
        for (int c0 = 0; c0 < N_NODES; c0 += (int)NC) {
            int nc = (int)((N_NODES - c0 < NC) ? (N_NODES - c0) : NC);
            k_mix2<<<(nc + 3) / 4, 256, 0, stream>>>(hcur, comp_l, row_start, edge_s, G, c0, nc);
            k_gemm3<<<(nc + 31) / 32, 256, 0, stream>>>(G, hcur, Bfl, bl, hnext, c0, nc);
        }
        float* tmp = hcur; hcur = hnext; hnext = tmp;
    }

    k_score<<<N_NODES / 4, 128, 0, stream>>>(hcur, er, W_attn, b_attn, w_sc, b_sc, af);
    k_starts<<<1, 256, 0, stream>>>(gid, starts);
    k_pool<<<NUM_GRAPHS, 128, 0, stream>>>(hcur, af, starts, w_out, b_out, out);
}